// Round 10
// baseline (835.927 us; speedup 1.0000x reference)
//
#include <hip/hip_runtime.h>

#define N_NODES 50000
#define N_EDGES 800000
#define D 128
#define NTILES 782          // ceil(50000/64)
#define BCAP 1408           // edges/bucket ~ Poisson(1024); +12 sigma
#define CAP 64              // per-node cap (fallback CSR path only)

typedef unsigned short ushort_t;
typedef unsigned int uint_t;
typedef __attribute__((ext_vector_type(8))) short bf16x8;
typedef __attribute__((ext_vector_type(4))) float f32x4;

// ---- full-path workspace layout (int element offsets into d_ws) ----
#define WS_CURSOR 0                              // 1024 ints (782 used)
#define WS_PAIRS  1024                           // NTILES*BCAP int2
#define WS_FB16   (WS_PAIRS + NTILES*BCAP*2)     // N_NODES*D/2 ints
#define WS_WB16   (WS_FB16 + N_NODES*D/2)        // D*D/2 ints
#define WS_FULL_BYTES ((size_t)(WS_WB16 + D*D/2) * 4)
// ---- fallback CSR layout ----
#define WS_COUNTS 0
#define WS_ESRC   50048
#define WS_CSR_BYTES ((size_t)(WS_ESRC + N_NODES * CAP) * 4)

__device__ inline uint_t pack2bf16(float lo, float hi) {
  uint_t ulo = __builtin_bit_cast(uint_t, lo);
  uint_t uhi = __builtin_bit_cast(uint_t, hi);
  ulo = (ulo + 0x7fffu + ((ulo >> 16) & 1u)) >> 16;          // RNE
  uhi = (uhi + 0x7fffu + ((uhi >> 16) & 1u)) & 0xffff0000u;  // RNE
  return ulo | uhi;
}

// ---------------------------------------------------------------------------
// Prep + partition (one dispatch, 3125 blocks):
//  - feature f32->bf16, W f32->bf16
//  - edge e -> bucket dst>>6, append (src,dst) via cursor atomics.
// Appends are sequential per bucket -> ~782 hot tail lines, ~6.4 MB writes
// (vs 51 MB write-allocate for the old scattered esrc build).
// cursor[] must be zeroed beforehand (hipMemsetAsync).
// ---------------------------------------------------------------------------
__global__ __launch_bounds__(256) void prep_part_kernel(
    const float* __restrict__ f, const float* __restrict__ W,
    const int* __restrict__ src, const int* __restrict__ dst,
    int* __restrict__ cursor, int2* __restrict__ pairs,
    ushort_t* __restrict__ fb, ushort_t* __restrict__ wb) {
  const int i = blockIdx.x * 256 + threadIdx.x;
  if (i < N_NODES * D / 8) {
    const float4 v0 = ((const float4*)f)[2 * i];
    const float4 v1 = ((const float4*)f)[2 * i + 1];
    uint_t r[4];
    r[0] = pack2bf16(v0.x, v0.y);
    r[1] = pack2bf16(v0.z, v0.w);
    r[2] = pack2bf16(v1.x, v1.y);
    r[3] = pack2bf16(v1.z, v1.w);
    *(uint4*)(fb + (size_t)i * 8) = *(const uint4*)r;
  }
  if (i < D * D / 8) {
    const float4 v0 = ((const float4*)W)[2 * i];
    const float4 v1 = ((const float4*)W)[2 * i + 1];
    uint_t r[4];
    r[0] = pack2bf16(v0.x, v0.y);
    r[1] = pack2bf16(v0.z, v0.w);
    r[2] = pack2bf16(v1.x, v1.y);
    r[3] = pack2bf16(v1.z, v1.w);
    *(uint4*)(wb + (size_t)i * 8) = *(const uint4*)r;
  }
  if (i < N_EDGES) {
    const int s = src[i];
    const int d = dst[i];
    const int t = d >> 6;
    const int pos = atomicAdd(&cursor[t], 1);
    if (pos < BCAP) pairs[(size_t)t * BCAP + pos] = make_int2(s, d);
  }
}

// ---------------------------------------------------------------------------
// Edge-driven gather with LDS accumulators + XCD slice affinity.
// blockIdx = j*8 + x; XCD = x; slice = x>>1 (32 cols); tile = j*2+(x&1).
// Per-XCD fb16 slice footprint = 50000*32*2B = 3.2 MB < 4 MB L2.
// Quad (4 lanes) per edge: lane owns 8 cols; ds_add_f32 into sAcc[64][33]
// (pad 33 -> quads on different rows hit different banks).
// ---------------------------------------------------------------------------
__global__ __launch_bounds__(256) void gather_lds_kernel(
    const ushort_t* __restrict__ fb16,
    const int* __restrict__ cursor,
    const int2* __restrict__ pairs,
    float* __restrict__ agg) {
  __shared__ float sAcc[64][33];  // 8.25 KB

  const int x     = blockIdx.x & 7;
  const int j     = blockIdx.x >> 3;
  const int tile  = j * 2 + (x & 1);
  const int slice = x >> 1;
  const int row0  = tile * 64;

  for (int i = threadIdx.x; i < 64 * 33; i += 256)
    ((float*)sAcc)[i] = 0.f;
  __syncthreads();

  int n = cursor[tile];
  if (n > BCAP) n = BCAP;
  const int q = threadIdx.x >> 2;   // quad id 0..63
  const int l = threadIdx.x & 3;    // lane in quad -> col block l*8
  const size_t pbase = (size_t)tile * BCAP;

  for (int e = q; e < n; e += 64) {
    const int2 p = pairs[pbase + e];  // 4 lanes same 8B (L1 broadcast)
    const uint4 w4 = *(const uint4*)(fb16 + (size_t)p.x * D + slice * 32 + l * 8);
    const uint_t ws[4] = {w4.x, w4.y, w4.z, w4.w};
    float* row = &sAcc[p.y & 63][l * 8];
#pragma unroll
    for (int t2 = 0; t2 < 4; ++t2) {
      atomicAdd(&row[2 * t2],     __builtin_bit_cast(float, ws[t2] << 16));
      atomicAdd(&row[2 * t2 + 1], __builtin_bit_cast(float, ws[t2] & 0xffff0000u));
    }
  }
  __syncthreads();

  const int r   = threadIdx.x >> 2;
  const int c0  = (threadIdx.x & 3) * 8;
  const int row = row0 + r;
  if (row < N_NODES) {
    const float* sp = &sAcc[r][c0];
    float* p = agg + (size_t)row * D + slice * 32 + c0;
    *(float4*)p       = make_float4(sp[0], sp[1], sp[2], sp[3]);
    *(float4*)(p + 4) = make_float4(sp[4], sp[5], sp[6], sp[7]);
  }
}

// ---------------------------------------------------------------------------
// In-place MFMA transform on d_out (proven Round 8/9): stage own 32 rows ->
// LDS -> sync -> z = relu(agg @ W^T + b) + feature -> overwrite same rows.
// C/D layout: col=lane&15, row=(lane>>4)*4+reg  [m89/m91].
// ---------------------------------------------------------------------------
#define RPB 32
__global__ __launch_bounds__(256) void transform_mfma_kernel(
    float* __restrict__ agg_out,
    const float* __restrict__ feature,
    const ushort_t* __restrict__ wb16,
    const float* __restrict__ b) {
  __shared__ float sA[RPB][D + 4];

  const int tid  = threadIdx.x;
  const int row0 = blockIdx.x * RPB;

  for (int i = tid; i < RPB * (D / 4); i += 256) {
    const int r  = i >> 5;
    const int c4 = (i & 31) * 4;
    const int row = row0 + r;
    float4 v = make_float4(0.f, 0.f, 0.f, 0.f);
    if (row < N_NODES) v = *(const float4*)(agg_out + (size_t)row * D + c4);
    *(float4*)&sA[r][c4] = v;
  }
  __syncthreads();

  const int wave = tid >> 6;
  const int lane = tid & 63;
  const int lr = lane & 15;
  const int lk = lane >> 4;

  f32x4 acc00 = {0.f, 0.f, 0.f, 0.f}, acc01 = acc00;
  f32x4 acc10 = acc00, acc11 = acc00;

#pragma unroll
  for (int ks = 0; ks < 4; ++ks) {
    bf16x8 afr[2];
#pragma unroll
    for (int mt = 0; mt < 2; ++mt) {
      const float* ap = &sA[mt * 16 + lr][ks * 32 + lk * 8];
      const float4 a0 = *(const float4*)ap;
      const float4 a1 = *(const float4*)(ap + 4);
      uint_t u[4];
      u[0] = pack2bf16(a0.x, a0.y);
      u[1] = pack2bf16(a0.z, a0.w);
      u[2] = pack2bf16(a1.x, a1.y);
      u[3] = pack2bf16(a1.z, a1.w);
      afr[mt] = __builtin_bit_cast(bf16x8, *(const uint4*)u);
    }
    bf16x8 bfr[2];
#pragma unroll
    for (int ntl = 0; ntl < 2; ++ntl) {
      const int col = (2 * wave + ntl) * 16 + lr;
      bfr[ntl] = *(const bf16x8*)(wb16 + (size_t)col * D + ks * 32 + lk * 8);
    }
    acc00 = __builtin_amdgcn_mfma_f32_16x16x32_bf16(afr[0], bfr[0], acc00, 0, 0, 0);
    acc01 = __builtin_amdgcn_mfma_f32_16x16x32_bf16(afr[0], bfr[1], acc01, 0, 0, 0);
    acc10 = __builtin_amdgcn_mfma_f32_16x16x32_bf16(afr[1], bfr[0], acc10, 0, 0, 0);
    acc11 = __builtin_amdgcn_mfma_f32_16x16x32_bf16(afr[1], bfr[1], acc11, 0, 0, 0);
  }

#pragma unroll
  for (int mt = 0; mt < 2; ++mt) {
#pragma unroll
    for (int ntl = 0; ntl < 2; ++ntl) {
      const f32x4 av = (mt == 0) ? (ntl == 0 ? acc00 : acc01)
                                 : (ntl == 0 ? acc10 : acc11);
      const int col = (2 * wave + ntl) * 16 + lr;
      const float bias = b[col];
#pragma unroll
      for (int jj = 0; jj < 4; ++jj) {
        const int row = row0 + mt * 16 + lk * 4 + jj;
        if (row < N_NODES) {
          const size_t o = (size_t)row * D + col;
          float z = av[jj] + bias;
          z = z > 0.f ? z : 0.f;
          agg_out[o] = z + feature[o];
        }
      }
    }
  }
}

// ---------------------------------------------------------------------------
// Fallback 1 (ws fits CSR only): Round 6 proven f32 CSR gather path.
// ---------------------------------------------------------------------------
__global__ __launch_bounds__(256) void build_kernel(const int* __restrict__ src,
                                                    const int* __restrict__ dst,
                                                    int* __restrict__ counts,
                                                    int* __restrict__ esrc) {
  const int e = blockIdx.x * 256 + threadIdx.x;
  if (e < N_EDGES) {
    const int d = dst[e];
    const int pos = atomicAdd(&counts[d], 1);
    if (pos < CAP) esrc[(size_t)d * CAP + pos] = src[e];
  }
}

__global__ __launch_bounds__(256) void gather_transform_f32_kernel(
    const float* __restrict__ feature,
    const int* __restrict__ counts,
    const int* __restrict__ esrc,
    const float* __restrict__ W,
    const float* __restrict__ b,
    float* __restrict__ out) {
  __shared__ float sA[RPB][D];
  const int tid  = threadIdx.x;
  const int row0 = blockIdx.x * RPB;
  const int l = tid & 15;
  const int g = tid >> 4;
#pragma unroll
  for (int p = 0; p < 2; ++p) {
    const int r   = p * 16 + g;
    const int row = row0 + r;
    float4 a0 = make_float4(0.f, 0.f, 0.f, 0.f);
    float4 a1 = make_float4(0.f, 0.f, 0.f, 0.f);
    if (row < N_NODES) {
      int cnt = counts[row];
      if (cnt > CAP) cnt = CAP;
      const size_t base = (size_t)row * CAP;
      for (int j0 = 0; j0 < cnt; j0 += 16) {
        int eid = 0;
        if (j0 + l < cnt) eid = esrc[base + j0 + l];
        const int lim = (cnt - j0 < 16) ? (cnt - j0) : 16;
        for (int k = 0; k < lim; ++k) {
          const int s = __shfl(eid, k, 16);
          const float* fp = feature + (size_t)s * D + l * 8;
          const float4 v0 = *(const float4*)fp;
          const float4 v1 = *(const float4*)(fp + 4);
          a0.x += v0.x; a0.y += v0.y; a0.z += v0.z; a0.w += v0.w;
          a1.x += v1.x; a1.y += v1.y; a1.z += v1.z; a1.w += v1.w;
        }
      }
    }
    float4* sp = (float4*)&sA[r][l * 8];
    sp[0] = a0; sp[1] = a1;
  }
  __syncthreads();
  const int c  = tid & 127;
  const int rh = tid >> 7;
  float acc[16];
#pragma unroll
  for (int r = 0; r < 16; ++r) acc[r] = 0.f;
  for (int k = 0; k < D; ++k) {
    const float wv = W[c * D + k];
#pragma unroll
    for (int r = 0; r < 16; ++r) acc[r] += sA[rh * 16 + r][k] * wv;
  }
  const float bias = b[c];
#pragma unroll
  for (int r = 0; r < 16; ++r) {
    const int row = row0 + rh * 16 + r;
    if (row < N_NODES) {
      const size_t o = (size_t)row * D + c;
      float z = acc[r] + bias;
      z = z > 0.f ? z : 0.f;
      out[o] = z + feature[o];
    }
  }
}

// ---------------------------------------------------------------------------
// Fallback 2: atomic scatter + in-place transform
// ---------------------------------------------------------------------------
__global__ __launch_bounds__(256) void scatter_kernel(
    const float* __restrict__ feature,
    const int* __restrict__ src,
    const int* __restrict__ dst,
    float* __restrict__ agg) {
  const long long total = (long long)N_EDGES * (D / 4);
  long long idx = (long long)blockIdx.x * blockDim.x + threadIdx.x;
  const long long stride = (long long)gridDim.x * blockDim.x;
  for (; idx < total; idx += stride) {
    const int e  = (int)(idx >> 5);
    const int c4 = ((int)idx & 31) * 4;
    const float4 v = *(const float4*)(feature + (long long)src[e] * D + c4);
    float* p = agg + (long long)dst[e] * D + c4;
    atomicAdd(p + 0, v.x);
    atomicAdd(p + 1, v.y);
    atomicAdd(p + 2, v.z);
    atomicAdd(p + 3, v.w);
  }
}

__global__ __launch_bounds__(256) void transform_kernel(
    float* __restrict__ agg_out,
    const float* __restrict__ feature,
    const float* __restrict__ W,
    const float* __restrict__ b) {
  __shared__ float sA[RPB][D];
  const int row0 = blockIdx.x * RPB;
  for (int i = threadIdx.x; i < RPB * (D / 4); i += 256) {
    const int r  = i >> 5;
    const int c4 = (i & 31) * 4;
    const int row = row0 + r;
    float4 v = make_float4(0.f, 0.f, 0.f, 0.f);
    if (row < N_NODES) v = *(const float4*)(agg_out + (long long)row * D + c4);
    *(float4*)&sA[r][c4] = v;
  }
  __syncthreads();
  const int c  = threadIdx.x & 127;
  const int rh = threadIdx.x >> 7;
  float acc[16];
#pragma unroll
  for (int r = 0; r < 16; ++r) acc[r] = 0.f;
  for (int k = 0; k < D; ++k) {
    const float wv = W[c * D + k];
#pragma unroll
    for (int r = 0; r < 16; ++r) acc[r] += sA[rh * 16 + r][k] * wv;
  }
  const float bias = b[c];
#pragma unroll
  for (int r = 0; r < 16; ++r) {
    const int row = row0 + rh * 16 + r;
    if (row < N_NODES) {
      const long long o = (long long)row * D + c;
      float z = acc[r] + bias;
      z = z > 0.f ? z : 0.f;
      agg_out[o] = z + feature[o];
    }
  }
}

extern "C" void kernel_launch(void* const* d_in, const int* in_sizes, int n_in,
                              void* d_out, int out_size, void* d_ws, size_t ws_size,
                              hipStream_t stream) {
  const float* feature = (const float*)d_in[0];
  const int*   src     = (const int*)d_in[1];
  const int*   dst     = (const int*)d_in[2];
  const float* W       = (const float*)d_in[3];
  const float* b       = (const float*)d_in[4];
  float* out = (float*)d_out;

  const int eblocks = (N_EDGES + 255) / 256;   // 3125
  const int nblocks = (N_NODES + RPB - 1) / RPB;

  if (ws_size >= WS_FULL_BYTES) {
    int*      wsi    = (int*)d_ws;
    int*      cursor = wsi + WS_CURSOR;
    int2*     pairs  = (int2*)(wsi + WS_PAIRS);
    ushort_t* fb16   = (ushort_t*)(wsi + WS_FB16);
    ushort_t* wb16   = (ushort_t*)(wsi + WS_WB16);

    hipMemsetAsync(cursor, 0, 1024 * 4, stream);
    prep_part_kernel<<<eblocks, 256, 0, stream>>>(feature, W, src, dst,
                                                  cursor, pairs, fb16, wb16);
    const int gje = (NTILES + 1) / 2;  // 391
    gather_lds_kernel<<<gje * 8, 256, 0, stream>>>(fb16, cursor, pairs, out);
    transform_mfma_kernel<<<nblocks, 256, 0, stream>>>(out, feature, wb16, b);
  } else if (ws_size >= WS_CSR_BYTES) {
    int* wsi    = (int*)d_ws;
    int* counts = wsi + WS_COUNTS;
    int* esrc   = wsi + WS_ESRC;

    hipMemsetAsync(counts, 0, (size_t)N_NODES * 4, stream);
    build_kernel<<<eblocks, 256, 0, stream>>>(src, dst, counts, esrc);
    gather_transform_f32_kernel<<<nblocks, 256, 0, stream>>>(feature, counts,
                                                             esrc, W, b, out);
  } else {
    hipMemsetAsync(out, 0, (size_t)N_NODES * D * sizeof(float), stream);
    scatter_kernel<<<2048, 256, 0, stream>>>(feature, src, dst, out);
    transform_kernel<<<nblocks, 256, 0, stream>>>(out, feature, W, b);
  }
}

// Round 11
// 192.944 us; speedup vs baseline: 4.3325x; 4.3325x over previous
//
#include <hip/hip_runtime.h>

#define N_NODES 50000
#define N_EDGES 800000
#define D 128
#define NTILES 782      // ceil(50000/64)
#define XCAP 16         // per-(node, block-class) bucket cap; lambda=2, P(>16)~1e-13
#define CAP 64          // fallback CSR path cap

typedef unsigned short ushort_t;
typedef unsigned int uint_t;
typedef __attribute__((ext_vector_type(8))) short bf16x8;
typedef __attribute__((ext_vector_type(4))) float f32x4;

// ---- full-path workspace layout (int element offsets into d_ws) ----
#define WS_COUNTS8 0                               // 8*50048 ints
#define WS_ESRC8   (8 * 50048)                     // 8*50000*16 ushorts = 3.2M ints
#define WS_FB16    (WS_ESRC8 + 3200000)            // N_NODES*D/2 ints
#define WS_WB16    (WS_FB16 + N_NODES * D / 2)     // D*D/2 ints
#define WS_FULL_BYTES ((size_t)(WS_WB16 + D * D / 2) * 4)   // ~27.2 MB
// ---- fallback CSR layout ----
#define WS_COUNTS 0
#define WS_ESRC   50048
#define WS_CSR_BYTES ((size_t)(WS_ESRC + N_NODES * CAP) * 4)

__device__ inline uint_t pack2bf16(float lo, float hi) {
  uint_t ulo = __builtin_bit_cast(uint_t, lo);
  uint_t uhi = __builtin_bit_cast(uint_t, hi);
  ulo = (ulo + 0x7fffu + ((ulo >> 16) & 1u)) >> 16;          // RNE
  uhi = (uhi + 0x7fffu + ((uhi >> 16) & 1u)) & 0xffff0000u;  // RNE
  return ulo | uhi;
}

// ---------------------------------------------------------------------------
// Prep + build (one dispatch, grid 3125*256 = 800000 exactly):
//  - feature f32->bf16 (item i = 8 floats), W f32->bf16
//  - edge i -> sub-bucket class x = blockIdx&7 (matches XCD under round-robin
//    dispatch) -> each bucket line dirtied by ONE XCD -> writes ~13 MB
//    (vs 48 MB for the single shared-bucket build of R8/R9).
// counts8[] zeroed beforehand via hipMemsetAsync.
// ---------------------------------------------------------------------------
__global__ __launch_bounds__(256) void prep_build_kernel(
    const float* __restrict__ f, const float* __restrict__ W,
    const int* __restrict__ src, const int* __restrict__ dst,
    int* __restrict__ counts8, ushort_t* __restrict__ esrc8,
    ushort_t* __restrict__ fb, ushort_t* __restrict__ wb) {
  const int i = blockIdx.x * 256 + threadIdx.x;   // 0..799999 (exact)
  {
    const float4 v0 = ((const float4*)f)[2 * i];
    const float4 v1 = ((const float4*)f)[2 * i + 1];
    uint_t r[4];
    r[0] = pack2bf16(v0.x, v0.y);
    r[1] = pack2bf16(v0.z, v0.w);
    r[2] = pack2bf16(v1.x, v1.y);
    r[3] = pack2bf16(v1.z, v1.w);
    *(uint4*)(fb + (size_t)i * 8) = *(const uint4*)r;
  }
  if (i < D * D / 8) {
    const float4 v0 = ((const float4*)W)[2 * i];
    const float4 v1 = ((const float4*)W)[2 * i + 1];
    uint_t r[4];
    r[0] = pack2bf16(v0.x, v0.y);
    r[1] = pack2bf16(v0.z, v0.w);
    r[2] = pack2bf16(v1.x, v1.y);
    r[3] = pack2bf16(v1.z, v1.w);
    *(uint4*)(wb + (size_t)i * 8) = *(const uint4*)r;
  }
  {
    const int s = src[i];
    const int d = dst[i];
    const int x = blockIdx.x & 7;
    const int pos = atomicAdd(&counts8[x * 50048 + d], 1);
    if (pos < XCAP)
      esrc8[(size_t)x * (N_NODES * XCAP) + d * XCAP + pos] = (ushort_t)s;
  }
}

// ---------------------------------------------------------------------------
// Column-sliced pull-aggregate with XCD affinity (R9-proven shape).
// blockIdx = j*8 + x; XCD = x; slice = x>>1 (32 cols); tile = j*2+(x&1).
// Per-XCD fb16 slice footprint = 50000*32*2B = 3.2 MB < 4 MB L2.
// 4-lane groups per node; lane owns 8 cols (one uint4 of bf16).
// Reads the 8 per-class sub-buckets of its node (counts prefetched).
// Writes f32 agg into d_out.
// ---------------------------------------------------------------------------
__global__ __launch_bounds__(256) void gather_slice_kernel(
    const ushort_t* __restrict__ fb16,
    const int* __restrict__ counts8,
    const ushort_t* __restrict__ esrc8,
    float* __restrict__ agg) {
  const int x     = blockIdx.x & 7;
  const int j     = blockIdx.x >> 3;
  const int tile  = j * 2 + (x & 1);
  const int slice = x >> 1;
  const int row0  = tile * 64;
  const int l = threadIdx.x & 3;     // lane in quad
  const int g = threadIdx.x >> 2;    // node within tile
  const int row = row0 + g;
  const int col0 = slice * 32 + l * 8;

  float a[8];
#pragma unroll
  for (int k = 0; k < 8; ++k) a[k] = 0.f;

  if (row < N_NODES) {
    int cn[8];
#pragma unroll
    for (int xx = 0; xx < 8; ++xx) {
      int c = counts8[xx * 50048 + row];
      cn[xx] = c > XCAP ? XCAP : c;
    }
#pragma unroll
    for (int xx = 0; xx < 8; ++xx) {
      const int cnt = cn[xx];
      const ushort_t* ep = esrc8 + (size_t)xx * (N_NODES * XCAP) + row * XCAP;
      for (int j0 = 0; j0 < cnt; j0 += 4) {
        int eid = 0;
        if (j0 + l < cnt) eid = ep[j0 + l];
        const int lim = (cnt - j0 < 4) ? (cnt - j0) : 4;
        for (int k = 0; k < lim; ++k) {
          const int s = __shfl(eid, k, 4);
          const uint4 w4 = *(const uint4*)(fb16 + (size_t)s * D + col0);
          const uint_t ws[4] = {w4.x, w4.y, w4.z, w4.w};
#pragma unroll
          for (int q = 0; q < 4; ++q) {
            a[2 * q]     += __builtin_bit_cast(float, ws[q] << 16);
            a[2 * q + 1] += __builtin_bit_cast(float, ws[q] & 0xffff0000u);
          }
        }
      }
    }
    float* p = agg + (size_t)row * D + col0;
    *(float4*)p       = make_float4(a[0], a[1], a[2], a[3]);
    *(float4*)(p + 4) = make_float4(a[4], a[5], a[6], a[7]);
  }
}

// ---------------------------------------------------------------------------
// In-place MFMA transform on d_out (proven R8/R9): stage own 32 rows -> LDS ->
// sync -> z = relu(agg @ W^T + b) + feature -> overwrite same rows.
// C/D layout: col=lane&15, row=(lane>>4)*4+reg  [m89/m91].
// ---------------------------------------------------------------------------
#define RPB 32
__global__ __launch_bounds__(256) void transform_mfma_kernel(
    float* __restrict__ agg_out,
    const float* __restrict__ feature,
    const ushort_t* __restrict__ wb16,
    const float* __restrict__ b) {
  __shared__ float sA[RPB][D + 4];

  const int tid  = threadIdx.x;
  const int row0 = blockIdx.x * RPB;

  for (int i = tid; i < RPB * (D / 4); i += 256) {
    const int r  = i >> 5;
    const int c4 = (i & 31) * 4;
    const int row = row0 + r;
    float4 v = make_float4(0.f, 0.f, 0.f, 0.f);
    if (row < N_NODES) v = *(const float4*)(agg_out + (size_t)row * D + c4);
    *(float4*)&sA[r][c4] = v;
  }
  __syncthreads();

  const int wave = tid >> 6;
  const int lane = tid & 63;
  const int lr = lane & 15;
  const int lk = lane >> 4;

  f32x4 acc00 = {0.f, 0.f, 0.f, 0.f}, acc01 = acc00;
  f32x4 acc10 = acc00, acc11 = acc00;

#pragma unroll
  for (int ks = 0; ks < 4; ++ks) {
    bf16x8 afr[2];
#pragma unroll
    for (int mt = 0; mt < 2; ++mt) {
      const float* ap = &sA[mt * 16 + lr][ks * 32 + lk * 8];
      const float4 a0 = *(const float4*)ap;
      const float4 a1 = *(const float4*)(ap + 4);
      uint_t u[4];
      u[0] = pack2bf16(a0.x, a0.y);
      u[1] = pack2bf16(a0.z, a0.w);
      u[2] = pack2bf16(a1.x, a1.y);
      u[3] = pack2bf16(a1.z, a1.w);
      afr[mt] = __builtin_bit_cast(bf16x8, *(const uint4*)u);
    }
    bf16x8 bfr[2];
#pragma unroll
    for (int ntl = 0; ntl < 2; ++ntl) {
      const int col = (2 * wave + ntl) * 16 + lr;
      bfr[ntl] = *(const bf16x8*)(wb16 + (size_t)col * D + ks * 32 + lk * 8);
    }
    acc00 = __builtin_amdgcn_mfma_f32_16x16x32_bf16(afr[0], bfr[0], acc00, 0, 0, 0);
    acc01 = __builtin_amdgcn_mfma_f32_16x16x32_bf16(afr[0], bfr[1], acc01, 0, 0, 0);
    acc10 = __builtin_amdgcn_mfma_f32_16x16x32_bf16(afr[1], bfr[0], acc10, 0, 0, 0);
    acc11 = __builtin_amdgcn_mfma_f32_16x16x32_bf16(afr[1], bfr[1], acc11, 0, 0, 0);
  }

#pragma unroll
  for (int mt = 0; mt < 2; ++mt) {
#pragma unroll
    for (int ntl = 0; ntl < 2; ++ntl) {
      const f32x4 av = (mt == 0) ? (ntl == 0 ? acc00 : acc01)
                                 : (ntl == 0 ? acc10 : acc11);
      const int col = (2 * wave + ntl) * 16 + lr;
      const float bias = b[col];
#pragma unroll
      for (int jj = 0; jj < 4; ++jj) {
        const int row = row0 + mt * 16 + lk * 4 + jj;
        if (row < N_NODES) {
          const size_t o = (size_t)row * D + col;
          float z = av[jj] + bias;
          z = z > 0.f ? z : 0.f;
          agg_out[o] = z + feature[o];
        }
      }
    }
  }
}

// ---------------------------------------------------------------------------
// Fallback 1 (ws fits CSR only): Round 6 proven f32 CSR gather path.
// ---------------------------------------------------------------------------
__global__ __launch_bounds__(256) void build_kernel(const int* __restrict__ src,
                                                    const int* __restrict__ dst,
                                                    int* __restrict__ counts,
                                                    int* __restrict__ esrc) {
  const int e = blockIdx.x * 256 + threadIdx.x;
  if (e < N_EDGES) {
    const int d = dst[e];
    const int pos = atomicAdd(&counts[d], 1);
    if (pos < CAP) esrc[(size_t)d * CAP + pos] = src[e];
  }
}

__global__ __launch_bounds__(256) void gather_transform_f32_kernel(
    const float* __restrict__ feature,
    const int* __restrict__ counts,
    const int* __restrict__ esrc,
    const float* __restrict__ W,
    const float* __restrict__ b,
    float* __restrict__ out) {
  __shared__ float sA[RPB][D];
  const int tid  = threadIdx.x;
  const int row0 = blockIdx.x * RPB;
  const int l = tid & 15;
  const int g = tid >> 4;
#pragma unroll
  for (int p = 0; p < 2; ++p) {
    const int r   = p * 16 + g;
    const int row = row0 + r;
    float4 a0 = make_float4(0.f, 0.f, 0.f, 0.f);
    float4 a1 = make_float4(0.f, 0.f, 0.f, 0.f);
    if (row < N_NODES) {
      int cnt = counts[row];
      if (cnt > CAP) cnt = CAP;
      const size_t base = (size_t)row * CAP;
      for (int j0 = 0; j0 < cnt; j0 += 16) {
        int eid = 0;
        if (j0 + l < cnt) eid = esrc[base + j0 + l];
        const int lim = (cnt - j0 < 16) ? (cnt - j0) : 16;
        for (int k = 0; k < lim; ++k) {
          const int s = __shfl(eid, k, 16);
          const float* fp = feature + (size_t)s * D + l * 8;
          const float4 v0 = *(const float4*)fp;
          const float4 v1 = *(const float4*)(fp + 4);
          a0.x += v0.x; a0.y += v0.y; a0.z += v0.z; a0.w += v0.w;
          a1.x += v1.x; a1.y += v1.y; a1.z += v1.z; a1.w += v1.w;
        }
      }
    }
    float4* sp = (float4*)&sA[r][l * 8];
    sp[0] = a0; sp[1] = a1;
  }
  __syncthreads();
  const int c  = tid & 127;
  const int rh = tid >> 7;
  float acc[16];
#pragma unroll
  for (int r = 0; r < 16; ++r) acc[r] = 0.f;
  for (int k = 0; k < D; ++k) {
    const float wv = W[c * D + k];
#pragma unroll
    for (int r = 0; r < 16; ++r) acc[r] += sA[rh * 16 + r][k] * wv;
  }
  const float bias = b[c];
#pragma unroll
  for (int r = 0; r < 16; ++r) {
    const int row = row0 + rh * 16 + r;
    if (row < N_NODES) {
      const size_t o = (size_t)row * D + c;
      float z = acc[r] + bias;
      z = z > 0.f ? z : 0.f;
      out[o] = z + feature[o];
    }
  }
}

// ---------------------------------------------------------------------------
// Fallback 2: atomic scatter + in-place transform
// ---------------------------------------------------------------------------
__global__ __launch_bounds__(256) void scatter_kernel(
    const float* __restrict__ feature,
    const int* __restrict__ src,
    const int* __restrict__ dst,
    float* __restrict__ agg) {
  const long long total = (long long)N_EDGES * (D / 4);
  long long idx = (long long)blockIdx.x * blockDim.x + threadIdx.x;
  const long long stride = (long long)gridDim.x * blockDim.x;
  for (; idx < total; idx += stride) {
    const int e  = (int)(idx >> 5);
    const int c4 = ((int)idx & 31) * 4;
    const float4 v = *(const float4*)(feature + (long long)src[e] * D + c4);
    float* p = agg + (long long)dst[e] * D + c4;
    atomicAdd(p + 0, v.x);
    atomicAdd(p + 1, v.y);
    atomicAdd(p + 2, v.z);
    atomicAdd(p + 3, v.w);
  }
}

__global__ __launch_bounds__(256) void transform_kernel(
    float* __restrict__ agg_out,
    const float* __restrict__ feature,
    const float* __restrict__ W,
    const float* __restrict__ b) {
  __shared__ float sA[RPB][D];
  const int row0 = blockIdx.x * RPB;
  for (int i = threadIdx.x; i < RPB * (D / 4); i += 256) {
    const int r  = i >> 5;
    const int c4 = (i & 31) * 4;
    const int row = row0 + r;
    float4 v = make_float4(0.f, 0.f, 0.f, 0.f);
    if (row < N_NODES) v = *(const float4*)(agg_out + (long long)row * D + c4);
    *(float4*)&sA[r][c4] = v;
  }
  __syncthreads();
  const int c  = threadIdx.x & 127;
  const int rh = threadIdx.x >> 7;
  float acc[16];
#pragma unroll
  for (int r = 0; r < 16; ++r) acc[r] = 0.f;
  for (int k = 0; k < D; ++k) {
    const float wv = W[c * D + k];
#pragma unroll
    for (int r = 0; r < 16; ++r) acc[r] += sA[rh * 16 + r][k] * wv;
  }
  const float bias = b[c];
#pragma unroll
  for (int r = 0; r < 16; ++r) {
    const int row = row0 + rh * 16 + r;
    if (row < N_NODES) {
      const long long o = (long long)row * D + c;
      float z = acc[r] + bias;
      z = z > 0.f ? z : 0.f;
      agg_out[o] = z + feature[o];
    }
  }
}

extern "C" void kernel_launch(void* const* d_in, const int* in_sizes, int n_in,
                              void* d_out, int out_size, void* d_ws, size_t ws_size,
                              hipStream_t stream) {
  const float* feature = (const float*)d_in[0];
  const int*   src     = (const int*)d_in[1];
  const int*   dst     = (const int*)d_in[2];
  const float* W       = (const float*)d_in[3];
  const float* b       = (const float*)d_in[4];
  float* out = (float*)d_out;

  const int eblocks = (N_EDGES + 255) / 256;   // 3125
  const int nblocks = (N_NODES + RPB - 1) / RPB;

  if (ws_size >= WS_FULL_BYTES) {
    int*      wsi     = (int*)d_ws;
    int*      counts8 = wsi + WS_COUNTS8;
    ushort_t* esrc8   = (ushort_t*)(wsi + WS_ESRC8);
    ushort_t* fb16    = (ushort_t*)(wsi + WS_FB16);
    ushort_t* wb16    = (ushort_t*)(wsi + WS_WB16);

    hipMemsetAsync(counts8, 0, (size_t)8 * 50048 * 4, stream);
    prep_build_kernel<<<eblocks, 256, 0, stream>>>(feature, W, src, dst,
                                                   counts8, esrc8, fb16, wb16);
    const int gje = (NTILES + 1) / 2;  // 391
    gather_slice_kernel<<<gje * 8, 256, 0, stream>>>(fb16, counts8, esrc8, out);
    transform_mfma_kernel<<<nblocks, 256, 0, stream>>>(out, feature, wb16, b);
  } else if (ws_size >= WS_CSR_BYTES) {
    int* wsi    = (int*)d_ws;
    int* counts = wsi + WS_COUNTS;
    int* esrc   = wsi + WS_ESRC;

    hipMemsetAsync(counts, 0, (size_t)N_NODES * 4, stream);
    build_kernel<<<eblocks, 256, 0, stream>>>(src, dst, counts, esrc);
    gather_transform_f32_kernel<<<nblocks, 256, 0, stream>>>(feature, counts,
                                                             esrc, W, b, out);
  } else {
    hipMemsetAsync(out, 0, (size_t)N_NODES * D * sizeof(float), stream);
    scatter_kernel<<<2048, 256, 0, stream>>>(feature, src, dst, out);
    transform_kernel<<<nblocks, 256, 0, stream>>>(out, feature, W, b);
  }
}